// Round 2
// baseline (422.912 us; speedup 1.0000x reference)
//
#include <hip/hip_runtime.h>

// DenseGINConv fused: out = mask * ( relu( ((1+eps)*x + adj@x) @ W1 + b1 ) @ W2 + b2 )
// B=64, N=1024, F_IN=64, F_HID=128, F_OUT=64, fp32 in/out.
//
// Round 7: break the per-chunk vmcnt(0) barrier drain (the structural ~20% stall:
// hipcc emits s_waitcnt vmcnt(0) before s_barrier for __syncthreads).
//  - Phase A now: 16 chunks of 64 j, depth-2 register pipeline:
//      iter c: issue adj(c+2) -> areg[c&1]; compute c (4 MFMA from LDS[c&1] +
//      xreg[c&1]); issue xt(c+2) -> xreg[c&1]; stage c+1 (counted vmcnt wait on
//      areg[(c+1)&1], loaded a FULL chunk period ago); lgkmcnt(0) + RAW s_barrier.
//    Global loads stay in flight across barriers (T4 counted-vmcnt idiom).
//  - Race analysis (1 barrier/chunk, dbuf): between barriers c and c+1 the only
//    LDS reads are buf[(c+1)&1], only writes are buf[c&1] -> disjoint. Sound.
//  - Phases B/C + epilogue + all m74/m101-verified MFMA layouts unchanged.
//
// LDS: adj bf16 dbuf 2x64x9 frags = 18432 B inside a 33792 B region (h1s aliases
// the full region in phases B/C) + hs 17408 B = 51200 B -> 3 blocks/CU.

#define N_     1024
#define FIN    64
#define FHID   128
#define FOUT   64
#define HS_LD  68
#define H1_LD  132
#define CH     64      // j-chunk size
#define NCHUNK 16      // 1024 / 64
#define KSPC   4       // k-steps (of 16) per chunk
#define FROW   9       // frags per adj row: 8 used + 1 pad -> 144 B stride
#define AUNITS 18      // 8-B units per adj row (16 used + 2 pad)
#define BUFU   1152    // 8-B units per buffer (64 * 18)

typedef __attribute__((ext_vector_type(16))) float f32x16;
typedef __attribute__((ext_vector_type(8)))  short s16x8;
typedef __attribute__((ext_vector_type(4)))  short s16x4;

__device__ inline short f2bf(float f) {
    union { float f; unsigned int u; } v; v.f = f;
    unsigned int r = v.u + 0x7fffu + ((v.u >> 16) & 1u);   // RNE
    return (short)(r >> 16);
}

// ---------------- pre-kernel: pack x -> bf16 B-fragment-major ----------------
// Row g = ((b*64 + ks)*2 + ng)*32 + n holds k=0..15 of B[n | ng] for k-step ks:
//   xt_row[g][k] = bf16( x[b][ks*16 + k][ng*32 + n] )
__global__ __launch_bounds__(256) void xt_pack(const float* __restrict__ x,
                                               s16x8* __restrict__ xt)
{
    const int g  = blockIdx.x * 256 + threadIdx.x;   // 0 .. 262143
    const int n  = g & 31;
    const int ng = (g >> 5) & 1;
    const int ks = (g >> 6) & 63;
    const int b  = g >> 12;
    const int f  = ng * 32 + n;

    s16x8 u0, u1;
    #pragma unroll
    for (int k = 0; k < 8; ++k)
        u0[k] = f2bf(x[(size_t)(b * N_ + ks * 16 + k) * FIN + f]);
    #pragma unroll
    for (int k = 0; k < 8; ++k)
        u1[k] = f2bf(x[(size_t)(b * N_ + ks * 16 + 8 + k) * FIN + f]);
    xt[2 * g]     = u0;
    xt[2 * g + 1] = u1;
}

// ---------------- main kernel ----------------
__global__ __launch_bounds__(256, 3) void gin_main(
    const float* __restrict__ x, const float* __restrict__ adj,
    const int* __restrict__ mask, const float* __restrict__ W1,
    const float* __restrict__ b1, const float* __restrict__ W2,
    const float* __restrict__ b2, const float* __restrict__ epsp,
    const s16x8* __restrict__ xt, float* __restrict__ out)
{
    __shared__ __align__(16) char region_raw[33792];   // adj dbuf (18432 B) / h1s (33792 B)
    __shared__ float hs[64 * HS_LD];

    auto   asf  = reinterpret_cast<s16x8 (*)[64][FROW]>(region_raw);
    s16x4* asf4 = reinterpret_cast<s16x4*>(region_raw);
    float* h1s  = reinterpret_cast<float*>(region_raw);

    const int t    = threadIdx.x;
    const int lane = t & 63;
    const int w    = t >> 6;
    const int b    = blockIdx.x >> 4;
    const int i0   = (blockIdx.x & 15) * 64;

    const float* xb   = x   + (size_t)b * N_ * FIN;
    const float* adjb = adj + (size_t)b * N_ * N_ + (size_t)i0 * N_;

    // 32x32x16 MFMA addressing (m74/m101-verified)
    const int l31  = lane & 31;
    const int half = lane >> 5;
    const int mrow = (w & 1) * 32;
    const int ncol = (w >> 1) * 32;
    const int ngq  = (w >> 1);

    // adj staging (coalesced): pass q covers row q*16 + (t>>4), cols (t&15)*4 .. +3
    const int rq16 = t >> 4;        // 0..15
    const int cl16 = t & 15;        // 0..15
    const float* adjA = adjb + (size_t)rq16 * N_ + cl16 * 4;

    // B-frag per-lane offset within a (b,ks,ng) 1 KB group (64 units)
    const int bfl = l31 * 2 + half;
    const size_t bgbase = (size_t)(b * 64) * 2 + ngq;   // group index = (b*64+ks)*2+ng

    f32x16 acc;
    #pragma unroll
    for (int r = 0; r < 16; ++r) acc[r] = 0.f;

    float4 areg[2][4];   // adj prefetch, 2 chunks in flight
    s16x8  xreg[2][4];   // B-frags, 2 chunks in flight

    // ---- prologue: issue chunks 0,1; stage chunk 0 ----
    #pragma unroll
    for (int q = 0; q < 4; ++q)
        areg[0][q] = *reinterpret_cast<const float4*>(adjA + (size_t)q * 16 * N_);
    #pragma unroll
    for (int q = 0; q < 4; ++q)
        areg[1][q] = *reinterpret_cast<const float4*>(adjA + (size_t)q * 16 * N_ + CH);
    #pragma unroll
    for (int s = 0; s < KSPC; ++s)
        xreg[0][s] = xt[(bgbase + (size_t)s * 2) * 64 + bfl];
    #pragma unroll
    for (int s = 0; s < KSPC; ++s)
        xreg[1][s] = xt[(bgbase + (size_t)(KSPC + s) * 2) * 64 + bfl];

    #pragma unroll
    for (int q = 0; q < 4; ++q) {                       // stage chunk 0 -> buffer 0
        s16x4 fr;
        fr[0] = f2bf(areg[0][q].x); fr[1] = f2bf(areg[0][q].y);
        fr[2] = f2bf(areg[0][q].z); fr[3] = f2bf(areg[0][q].w);
        asf4[(q * 16 + rq16) * AUNITS + cl16] = fr;
    }
    asm volatile("s_waitcnt lgkmcnt(0)" ::: "memory");
    __builtin_amdgcn_s_barrier();

    // ---- depth-2 pipelined chunk loop (raw barriers: NO vmcnt drain) ----
    #pragma unroll
    for (int c = 0; c < NCHUNK; ++c) {
        if (c + 2 < NCHUNK) {
            #pragma unroll
            for (int q = 0; q < 4; ++q)
                areg[c & 1][q] = *reinterpret_cast<const float4*>(
                    adjA + (size_t)q * 16 * N_ + (size_t)(c + 2) * CH);
        }
        // compute chunk c
        #pragma unroll
        for (int s = 0; s < KSPC; ++s) {
            const s16x8 a = asf[c & 1][mrow + l31][2 * s + half];
            acc = __builtin_amdgcn_mfma_f32_32x32x16_bf16(a, xreg[c & 1][s], acc, 0, 0, 0);
        }
        if (c + 2 < NCHUNK) {
            #pragma unroll
            for (int s = 0; s < KSPC; ++s)
                xreg[c & 1][s] = xt[(bgbase + (size_t)((c + 2) * KSPC + s) * 2) * 64 + bfl];
        }
        if (c + 1 < NCHUNK) {
            // stage chunk c+1 (counted vmcnt wait on areg[(c+1)&1] only)
            const int boff = ((c + 1) & 1) * BUFU;
            #pragma unroll
            for (int q = 0; q < 4; ++q) {
                const float4 u = areg[(c + 1) & 1][q];
                s16x4 fr;
                fr[0] = f2bf(u.x); fr[1] = f2bf(u.y);
                fr[2] = f2bf(u.z); fr[3] = f2bf(u.w);
                asf4[boff + (q * 16 + rq16) * AUNITS + cl16] = fr;
            }
            asm volatile("s_waitcnt lgkmcnt(0)" ::: "memory");
            __builtin_amdgcn_s_barrier();
        }
    }

    // h = (1+eps)*x + agg -> hs  (C/D: col=lane&31, row=(reg&3)+8*(reg>>2)+4*half)
    {
        const float se = 1.0f + epsp[0];
        const int col = ncol + l31;
        #pragma unroll
        for (int reg = 0; reg < 16; ++reg) {
            const int row = mrow + (reg & 3) + 8 * (reg >> 2) + 4 * half;
            const float xv = xb[(size_t)(i0 + row) * FIN + col];
            hs[row * HS_LD + col] = acc[reg] + se * xv;
        }
    }
    __syncthreads();

    // ---------------- Phase B: h1 = relu(h @ W1 + b1) ----------------
    {
        const int k4 = (t & 31) * 4;
        const int rb = (t >> 5) * 8;
        float4 hacc[8];
        const float4 b1v = *reinterpret_cast<const float4*>(b1 + k4);
        #pragma unroll
        for (int r = 0; r < 8; ++r) hacc[r] = b1v;

        #pragma unroll 4
        for (int j = 0; j < FIN; ++j) {
            const float4 w1v = *reinterpret_cast<const float4*>(W1 + j * FHID + k4);
            #pragma unroll
            for (int r = 0; r < 8; ++r) {
                const float hv = hs[(rb + r) * HS_LD + j];
                hacc[r].x += hv * w1v.x; hacc[r].y += hv * w1v.y;
                hacc[r].z += hv * w1v.z; hacc[r].w += hv * w1v.w;
            }
        }
        #pragma unroll
        for (int r = 0; r < 8; ++r) {
            float4 v;
            v.x = fmaxf(hacc[r].x, 0.f); v.y = fmaxf(hacc[r].y, 0.f);
            v.z = fmaxf(hacc[r].z, 0.f); v.w = fmaxf(hacc[r].w, 0.f);
            *reinterpret_cast<float4*>(&h1s[(rb + r) * H1_LD + k4]) = v;
        }
    }
    __syncthreads();

    // ---------------- Phase C: out = mask * (h1 @ W2 + b2) ----------------
    {
        const int fi = (t & 15) * 4;
        const int ri = (t >> 4) * 4;
        float4 oacc[4];
        const float4 b2v = *reinterpret_cast<const float4*>(b2 + fi);
        #pragma unroll
        for (int ii = 0; ii < 4; ++ii) oacc[ii] = b2v;

        #pragma unroll 4
        for (int j = 0; j < FHID; ++j) {
            const float4 w2v = *reinterpret_cast<const float4*>(W2 + j * FOUT + fi);
            #pragma unroll
            for (int ii = 0; ii < 4; ++ii) {
                const float hv = h1s[(ri + ii) * H1_LD + j];
                oacc[ii].x += hv * w2v.x; oacc[ii].y += hv * w2v.y;
                oacc[ii].z += hv * w2v.z; oacc[ii].w += hv * w2v.w;
            }
        }
        #pragma unroll
        for (int ii = 0; ii < 4; ++ii) {
            const int gi = i0 + ri + ii;
            const int m  = mask[b * N_ + gi];
            float4 o = oacc[ii];
            if (!m) o = make_float4(0.f, 0.f, 0.f, 0.f);
            *reinterpret_cast<float4*>(out + ((size_t)b * N_ + gi) * FOUT + fi) = o;
        }
    }
}

extern "C" void kernel_launch(void* const* d_in, const int* in_sizes, int n_in,
                              void* d_out, int out_size, void* d_ws, size_t ws_size,
                              hipStream_t stream) {
    const float* x    = (const float*)d_in[0];
    const float* adj  = (const float*)d_in[1];
    const int*   mask = (const int*)  d_in[2];
    const float* W1   = (const float*)d_in[3];
    const float* b1   = (const float*)d_in[4];
    const float* W2   = (const float*)d_in[5];
    const float* b2   = (const float*)d_in[6];
    const float* eps  = (const float*)d_in[7];
    float* out = (float*)d_out;
    s16x8* xt = (s16x8*)d_ws;   // 8 MB: 524288 units

    xt_pack<<<dim3(1024), dim3(256), 0, stream>>>(x, xt);
    gin_main<<<dim3(64 * 16), dim3(256), 0, stream>>>(x, adj, mask, W1, b1, W2, b2, eps, xt, out);
}